// Round 7
// baseline (769.256 us; speedup 1.0000x reference)
//
#include <hip/hip_runtime.h>

typedef __bf16 bf16x8 __attribute__((ext_vector_type(8)));
typedef float  f32x4  __attribute__((ext_vector_type(4)));

#define B_    8
#define NB_   1024
#define C_    1024
#define T_    32
#define D_    1024
#define M_    (B_ * NB_)      // 8192
#define N3_   (3 * D_)        // 3072
#define WIN_  9
#define HALF_ 4

// Async global->LDS, 16 B per lane. LDS dest is wave-uniform base; HW writes
// lane l at base + l*16. AS casts via integer round-trip.
__device__ __forceinline__ void gload_lds16(const void* g, void* l) {
    __builtin_amdgcn_global_load_lds(
        (const __attribute__((address_space(1))) void*)(unsigned long long)(uintptr_t)g,
        (__attribute__((address_space(3))) void*)(unsigned int)(uintptr_t)l,
        16, 0, 0);
}

// ---------------------------------------------------------------------------
// Kernel 1: tokens = mean(xb, axis=-1), cast to bf16.
// Grid-stride, 2048 blocks. 8 lanes per output; 1 KB contiguous per wave-iter.
// ---------------------------------------------------------------------------
__global__ __launch_bounds__(256) void mean_kernel(const float* __restrict__ xb,
                                                   __bf16* __restrict__ tok) {
    const int OUT = M_ * C_;                    // 8,388,608 outputs
    int lane  = threadIdx.x & 63;
    int chunk = lane & 7;
    int sub   = lane >> 3;                      // 0..7: output within wave-iter
    int gw = (blockIdx.x * 256 + threadIdx.x) >> 6;   // global wave id
    int nw = (gridDim.x * 256) >> 6;                  // total waves
    for (int o8 = gw * 8; o8 < OUT; o8 += nw * 8) {
        int o = o8 + sub;
        const f32x4* p = (const f32x4*)(xb + (size_t)o * T_ + chunk * 4);
        f32x4 v = __builtin_nontemporal_load(p);
        float s = v.x + v.y + v.z + v.w;
        s += __shfl_xor(s, 1);
        s += __shfl_xor(s, 2);
        s += __shfl_xor(s, 4);
        if (chunk == 0) tok[o] = (__bf16)(s * (1.0f / 32.0f));
    }
}

// ---------------------------------------------------------------------------
// Kernel 2: transpose W (K x N fp32) -> Wt (N x K bf16). 4 matrices:
// z=0..2 -> Wq,Wk,Wv into Wqkvt (3072 x 1024); z=3 -> Wo into Wot.
// ---------------------------------------------------------------------------
__global__ __launch_bounds__(256) void transpose_kernel(
    const float* __restrict__ Wq, const float* __restrict__ Wk,
    const float* __restrict__ Wv, const float* __restrict__ Wo,
    __bf16* __restrict__ Wqkvt, __bf16* __restrict__ Wot) {
    __shared__ float tile[32][33];
    int mat = blockIdx.z;
    const float* src = (mat == 0) ? Wq : (mat == 1) ? Wk : (mat == 2) ? Wv : Wo;
    __bf16* dst = (mat < 3) ? (Wqkvt + (size_t)mat * 1024 * 1024) : Wot;
    int tx = threadIdx.x, ty = threadIdx.y;
    int x  = blockIdx.x * 32 + tx;   // source col (n)
    int y0 = blockIdx.y * 32;        // source row base (k)
#pragma unroll
    for (int j = 0; j < 32; j += 8)
        tile[ty + j][tx] = src[(size_t)(y0 + ty + j) * 1024 + x];
    __syncthreads();
    int k = y0 + tx;
#pragma unroll
    for (int j = 0; j < 32; j += 8) {
        int n = blockIdx.x * 32 + ty + j;
        dst[(size_t)n * 1024 + k] = (__bf16)tile[tx][ty + j];
    }
}

// ---------------------------------------------------------------------------
// Kernel 3/5: bf16 MFMA GEMM, 128x128 tile, counted-vmcnt 3-slot pipeline
// (R5 sync structure, verified) + CONFLICT-FREE k-group-major LDS layout.
//
// Layout: each 16-row segment s is [kg=4][row=16][8 bf16] (1024 B). Staging
// lane l supplies global (row = l&15, colgroup = l>>4); gload_lds writes lane
// l at seg_base + l*16, so chunk index = kg*16 + row. Fragment ds_read_b128:
// lane addr = seg*1024 + lg*256 + l15*16 -> the wave's 64 lanes cover 1024
// CONSECUTIVE bytes = stride-1 conflict-free (vs 8-way conflict of the
// row-major [128][32] layout whose 64-B row stride aliased banks {0-3,16-19}).
//
// Per iter: vmcnt(4) -> s_barrier -> ds_read tile t -> stage t+2 ->
// setprio(1) MFMA setprio(0). Loads never drain to 0 in steady state (T4).
// XCD-bijective block swizzle (T1).
// MODE 0: C += pos (broadcast over b), write bf16 (QKV).
// MODE 1: write fp32 correction matrix corr[row, col].
// ---------------------------------------------------------------------------
template <int MODE>
__global__ __launch_bounds__(256) void gemm_kernel(
    const __bf16* __restrict__ A, const __bf16* __restrict__ Bt,
    int K, int Ncols,
    const float* __restrict__ pos, __bf16* __restrict__ Cbf,
    float* __restrict__ corr) {
    constexpr int BM = 128, BK = 32, KT = 32;   // K = 1024 fixed
    __shared__ __align__(16) __bf16 As[3][BM * BK];   // 3 x 8 KB
    __shared__ __align__(16) __bf16 Bs[3][BM * BK];   // 3 x 8 KB
    int tid = threadIdx.x;
    int wid = tid >> 6, lane = tid & 63;
    int wr = wid >> 1, wc = wid & 1;
    int l15 = lane & 15, lg = lane >> 4;

    // XCD-bijective swizzle: nwg % 8 == 0 for both gemms (1536, 512).
    int q = gridDim.x >> 3;
    int wg = (blockIdx.x & 7) * q + (blockIdx.x >> 3);
    int row0 = (wg & 63) * BM;        // M/BM = 64 for both gemms
    int col0 = (wg >> 6) * BM;

    // k-group-major staging lane map (see header comment)
    int srow = lane & 15;
    int scol = (lane >> 4) * 8;

    f32x4 acc[4][4] = {};

    // stage tile t into slot: wave w supplies segments {w, w+4}; lane l's 16 B
    // land at seg_base + l*16 = [4][16][8] k-group-major chunk.
    auto STAGE = [&](int t, int slot) {
#pragma unroll
        for (int i = 0; i < 2; i++) {
            int s = wid + i * 4;
            gload_lds16(A  + (size_t)(row0 + s * 16 + srow) * K + t * BK + scol, &As[slot][s * 512]);
            gload_lds16(Bt + (size_t)(col0 + s * 16 + srow) * K + t * BK + scol, &Bs[slot][s * 512]);
        }
    };

    STAGE(0, 0);
    STAGE(1, 1);

    for (int t = 0; t < KT; ++t) {
        int slot = t % 3;
        // Own-wave bound on tile t's 4 loads; barrier join makes all waves'
        // tile-t data visible after the barrier.
        if (t == KT - 1) asm volatile("s_waitcnt vmcnt(0)" ::: "memory");
        else             asm volatile("s_waitcnt vmcnt(4)" ::: "memory");
        __builtin_amdgcn_s_barrier();
        __builtin_amdgcn_sched_barrier(0);
        // ds_reads first: their lgkm latency hides under the STAGE VMEM issues.
        // A-frag (row = wr*64 + m*16 + l15, kg = lg) lives in segment wr*4+m
        // at element offset lg*128 + l15*8 -> wave reads 1024 consecutive B.
        bf16x8 fa[4], fb[4];
#pragma unroll
        for (int m = 0; m < 4; m++)
            fa[m] = *(const bf16x8*)&As[slot][(wr * 4 + m) * 512 + lg * 128 + l15 * 8];
#pragma unroll
        for (int n = 0; n < 4; n++)
            fb[n] = *(const bf16x8*)&Bs[slot][(wc * 4 + n) * 512 + lg * 128 + l15 * 8];
        if (t + 2 < KT) STAGE(t + 2, (t + 2) % 3);
        __builtin_amdgcn_s_setprio(1);
#pragma unroll
        for (int m = 0; m < 4; m++)
#pragma unroll
            for (int n = 0; n < 4; n++)
                acc[m][n] = __builtin_amdgcn_mfma_f32_16x16x32_bf16(fa[m], fb[n], acc[m][n], 0, 0, 0);
        __builtin_amdgcn_s_setprio(0);
    }

#pragma unroll
    for (int m = 0; m < 4; m++) {
#pragma unroll
        for (int n = 0; n < 4; n++) {
            int col = col0 + wc * 64 + n * 16 + l15;
#pragma unroll
            for (int r = 0; r < 4; r++) {
                int row = row0 + wr * 64 + m * 16 + lg * 4 + r;
                float v = acc[m][n][r];
                if (MODE == 0) {
                    v += pos[((row & 1023) << 10) + (col & 1023)];
                    Cbf[(size_t)row * Ncols + col] = (__bf16)v;
                } else {
                    corr[(size_t)row * 1024 + col] = v;
                }
            }
        }
    }
}

// ---------------------------------------------------------------------------
// Kernel 4: windowed attention. One wave per (b, n). QKV row = Q|K|V bf16.
// scores over 9 clipped neighbors, softmax in-register, ctx written bf16.
// ---------------------------------------------------------------------------
__global__ __launch_bounds__(256) void attn_kernel(const __bf16* __restrict__ QKV,
                                                   __bf16* __restrict__ ctx) {
    int wg   = blockIdx.x * 4 + (threadIdx.x >> 6);  // = b*1024 + n
    int lane = threadIdx.x & 63;
    int n = wg & 1023;
    int browbase = wg - n;  // b*1024

    const __bf16* qrow = QKV + (size_t)wg * N3_;
    bf16x8 q0 = *(const bf16x8*)(qrow + lane * 8);
    bf16x8 q1 = *(const bf16x8*)(qrow + 512 + lane * 8);
    float qf[16];
#pragma unroll
    for (int i = 0; i < 8; i++) { qf[i] = (float)q0[i]; qf[8 + i] = (float)q1[i]; }

    float sc[WIN_];
#pragma unroll
    for (int w = 0; w < WIN_; w++) {
        int nn = n - HALF_ + w;
        nn = (nn < 0) ? 0 : (nn > 1023 ? 1023 : nn);
        const __bf16* krow = QKV + (size_t)(browbase + nn) * N3_ + D_;
        bf16x8 k0 = *(const bf16x8*)(krow + lane * 8);
        bf16x8 k1 = *(const bf16x8*)(krow + 512 + lane * 8);
        float s = 0.f;
#pragma unroll
        for (int i = 0; i < 8; i++)
            s += qf[i] * (float)k0[i] + qf[8 + i] * (float)k1[i];
        s += __shfl_xor(s, 32); s += __shfl_xor(s, 16); s += __shfl_xor(s, 8);
        s += __shfl_xor(s, 4);  s += __shfl_xor(s, 2);  s += __shfl_xor(s, 1);
        sc[w] = s * 0.03125f;  // 1/sqrt(1024)
    }

    float mx = sc[0];
#pragma unroll
    for (int w = 1; w < WIN_; w++) mx = fmaxf(mx, sc[w]);
    float e[WIN_], sum = 0.f;
#pragma unroll
    for (int w = 0; w < WIN_; w++) { e[w] = __expf(sc[w] - mx); sum += e[w]; }
    float inv = 1.0f / sum;

    float accv[16];
#pragma unroll
    for (int i = 0; i < 16; i++) accv[i] = 0.f;
#pragma unroll
    for (int w = 0; w < WIN_; w++) {
        int nn = n - HALF_ + w;
        nn = (nn < 0) ? 0 : (nn > 1023 ? 1023 : nn);
        const __bf16* vrow = QKV + (size_t)(browbase + nn) * N3_ + 2 * D_;
        bf16x8 v0 = *(const bf16x8*)(vrow + lane * 8);
        bf16x8 v1 = *(const bf16x8*)(vrow + 512 + lane * 8);
        float aw = e[w] * inv;
#pragma unroll
        for (int i = 0; i < 8; i++) {
            accv[i]     += aw * (float)v0[i];
            accv[8 + i] += aw * (float)v1[i];
        }
    }

    bf16x8 o0, o1;
#pragma unroll
    for (int i = 0; i < 8; i++) { o0[i] = (__bf16)accv[i]; o1[i] = (__bf16)accv[8 + i]; }
    __bf16* crow = ctx + (size_t)wg * D_;
    *(bf16x8*)(crow + lane * 8) = o0;
    *(bf16x8*)(crow + 512 + lane * 8) = o1;
}

// ---------------------------------------------------------------------------
// Kernel 6: out[rc, t] = xb[rc, t] + corr[rc], flat float4 grid-stride.
// Nontemporal on the pure streams (xb, out); corr stays cached.
// ---------------------------------------------------------------------------
__global__ __launch_bounds__(256) void add_kernel(const float* __restrict__ xb,
                                                  const float* __restrict__ corr,
                                                  float* __restrict__ outp) {
    const long long total4 = (long long)M_ * C_ * T_ / 4;   // 67,108,864
    long long stride = (long long)gridDim.x * 256;
#pragma unroll 4
    for (long long i = (long long)blockIdx.x * 256 + threadIdx.x; i < total4; i += stride) {
        float c = corr[i >> 3];                 // 8 lanes share one corr value
        f32x4 x = __builtin_nontemporal_load((const f32x4*)xb + i);
        x.x += c; x.y += c; x.z += c; x.w += c;
        __builtin_nontemporal_store(x, (f32x4*)outp + i);
    }
}

// ---------------------------------------------------------------------------
extern "C" void kernel_launch(void* const* d_in, const int* in_sizes, int n_in,
                              void* d_out, int out_size, void* d_ws, size_t ws_size,
                              hipStream_t stream) {
    const float* xb  = (const float*)d_in[0];
    const float* Wq  = (const float*)d_in[1];
    const float* Wk  = (const float*)d_in[2];
    const float* Wv  = (const float*)d_in[3];
    const float* Wo  = (const float*)d_in[4];
    const float* pos = (const float*)d_in[5];
    float* out = (float*)d_out;

    char* ws = (char*)d_ws;
    // workspace layout (bytes)
    __bf16* tokens = (__bf16*)(ws);                       // M*1024*2      = 16 MB
    __bf16* wqkvt  = (__bf16*)(ws + 16777216);            // 3072*1024*2   = 6 MB
    __bf16* wot    = (__bf16*)(ws + 23068672);            // 1024*1024*2   = 2 MB
    __bf16* qkv    = (__bf16*)(ws + 25165824);            // M*3072*2      = 48 MB
    __bf16* ctx    = (__bf16*)(ws + 75497472);            // M*1024*2      = 16 MB
    float*  corr   = (float*)(ws + 25165824);             // reuse qkv: M*1024*4 = 32 MB
    // total 88 MB

    // 1. tokens = mean(xb, T)   (grid-stride, 2048 blocks)
    mean_kernel<<<dim3(2048), dim3(256), 0, stream>>>(xb, tokens);

    // 2. weight transpose + bf16 cast
    transpose_kernel<<<dim3(32, 32, 4), dim3(32, 8), 0, stream>>>(Wq, Wk, Wv, Wo, wqkvt, wot);

    // 3. QKV = tokens @ [Wq|Wk|Wv] + pos   (grid flattened 1D: 64 x 24 = 1536)
    gemm_kernel<0><<<dim3(1536), dim3(256), 0, stream>>>(
        tokens, wqkvt, 1024, N3_, pos, qkv, nullptr);

    // 4. windowed attention -> ctx
    attn_kernel<<<dim3(M_ / 4), dim3(256), 0, stream>>>(qkv, ctx);

    // 5. corr = ctx @ Wo  (fp32, 32 MB; overwrites dead qkv region; 64 x 8 = 512)
    gemm_kernel<1><<<dim3(512), dim3(256), 0, stream>>>(
        ctx, wot, 1024, C_, nullptr, nullptr, corr);

    // 6. out = xb + corr (broadcast over T)  (8192 blocks for TLP)
    add_kernel<<<dim3(8192), dim3(256), 0, stream>>>(xb, corr, out);
}

// Round 8
// 752.305 us; speedup vs baseline: 1.0225x; 1.0225x over previous
//
#include <hip/hip_runtime.h>

typedef __bf16 bf16x8 __attribute__((ext_vector_type(8)));
typedef float  f32x4  __attribute__((ext_vector_type(4)));

#define B_    8
#define NB_   1024
#define C_    1024
#define T_    32
#define D_    1024
#define M_    (B_ * NB_)      // 8192
#define N3_   (3 * D_)        // 3072
#define WIN_  9
#define HALF_ 4

// Async global->LDS, 16 B per lane. LDS dest is wave-uniform base; HW writes
// lane l at base + l*16. AS casts via integer round-trip.
__device__ __forceinline__ void gload_lds16(const void* g, void* l) {
    __builtin_amdgcn_global_load_lds(
        (const __attribute__((address_space(1))) void*)(unsigned long long)(uintptr_t)g,
        (__attribute__((address_space(3))) void*)(unsigned int)(uintptr_t)l,
        16, 0, 0);
}

// ---------------------------------------------------------------------------
// Kernel 1: tokens = mean(xb, axis=-1), cast to bf16.
// Grid-stride, 2048 blocks. 8 lanes per output; 1 KB contiguous per wave-iter.
// ---------------------------------------------------------------------------
__global__ __launch_bounds__(256) void mean_kernel(const float* __restrict__ xb,
                                                   __bf16* __restrict__ tok) {
    const int OUT = M_ * C_;                    // 8,388,608 outputs
    int lane  = threadIdx.x & 63;
    int chunk = lane & 7;
    int sub   = lane >> 3;                      // 0..7: output within wave-iter
    int gw = (blockIdx.x * 256 + threadIdx.x) >> 6;   // global wave id
    int nw = (gridDim.x * 256) >> 6;                  // total waves
    for (int o8 = gw * 8; o8 < OUT; o8 += nw * 8) {
        int o = o8 + sub;
        const f32x4* p = (const f32x4*)(xb + (size_t)o * T_ + chunk * 4);
        f32x4 v = __builtin_nontemporal_load(p);
        float s = v.x + v.y + v.z + v.w;
        s += __shfl_xor(s, 1);
        s += __shfl_xor(s, 2);
        s += __shfl_xor(s, 4);
        if (chunk == 0) tok[o] = (__bf16)(s * (1.0f / 32.0f));
    }
}

// ---------------------------------------------------------------------------
// Kernel 2: transpose W (K x N fp32) -> Wt (N x K bf16). 4 matrices:
// z=0..2 -> Wq,Wk,Wv into Wqkvt (3072 x 1024); z=3 -> Wo into Wot.
// ---------------------------------------------------------------------------
__global__ __launch_bounds__(256) void transpose_kernel(
    const float* __restrict__ Wq, const float* __restrict__ Wk,
    const float* __restrict__ Wv, const float* __restrict__ Wo,
    __bf16* __restrict__ Wqkvt, __bf16* __restrict__ Wot) {
    __shared__ float tile[32][33];
    int mat = blockIdx.z;
    const float* src = (mat == 0) ? Wq : (mat == 1) ? Wk : (mat == 2) ? Wv : Wo;
    __bf16* dst = (mat < 3) ? (Wqkvt + (size_t)mat * 1024 * 1024) : Wot;
    int tx = threadIdx.x, ty = threadIdx.y;
    int x  = blockIdx.x * 32 + tx;   // source col (n)
    int y0 = blockIdx.y * 32;        // source row base (k)
#pragma unroll
    for (int j = 0; j < 32; j += 8)
        tile[ty + j][tx] = src[(size_t)(y0 + ty + j) * 1024 + x];
    __syncthreads();
    int k = y0 + tx;
#pragma unroll
    for (int j = 0; j < 32; j += 8) {
        int n = blockIdx.x * 32 + ty + j;
        dst[(size_t)n * 1024 + k] = (__bf16)tile[tx][ty + j];
    }
}

// ---------------------------------------------------------------------------
// Kernel 3/5: bf16 MFMA GEMM, 128x128 tile, counted-vmcnt 3-slot pipeline
// (R5 sync structure) + XOR-swizzled LDS (both-sides involution, rule #21).
//
// Staging lane map: srow = lane>>2 (4 consecutive lanes per row -> one 64 B
// strip per 4-lane group, R5's coalescing), chunk-XOR scol = ((lane&3) ^
// ((lane>>3)&3))*8 -- permutes 16 B chunks WITHIN the same 64 B line (zero
// fetch cost). gload_lds writes lane l linearly at seg*1024 + l*16.
// Chunk c thus holds global (row = c>>2, kg = (c&3) ^ f(c>>2)), f(r)=(r>>1)&3.
//
// Fragment read: lane (l15,lg) wants (row=l15, kg=lg) -> chunk l15*4 +
// (lg ^ f(l15)); byte addr = l15*64 + (lg^f)*16. The 8 same-parity l15 lanes
// at fixed lg hit each 16 B slot exactly twice -> 2-way on every bank = free
// (m136), vs 8-way for the unswizzled row-major layout.
//
// Per iter: vmcnt(4) -> s_barrier -> ds_read t -> stage t+2 -> setprio MFMA.
// Loads never drain to 0 in steady state (T4). XCD-bijective swizzle (T1).
// MODE 0: C += pos (broadcast over b), write bf16 (QKV).
// MODE 1: write fp32 correction matrix corr[row, col].
// ---------------------------------------------------------------------------
template <int MODE>
__global__ __launch_bounds__(256) void gemm_kernel(
    const __bf16* __restrict__ A, const __bf16* __restrict__ Bt,
    int K, int Ncols,
    const float* __restrict__ pos, __bf16* __restrict__ Cbf,
    float* __restrict__ corr) {
    constexpr int BM = 128, BK = 32, KT = 32;   // K = 1024 fixed
    __shared__ __align__(16) __bf16 As[3][BM * BK];   // 3 x 8 KB
    __shared__ __align__(16) __bf16 Bs[3][BM * BK];   // 3 x 8 KB
    int tid = threadIdx.x;
    int wid = tid >> 6, lane = tid & 63;
    int wr = wid >> 1, wc = wid & 1;
    int l15 = lane & 15, lg = lane >> 4;

    // XCD-bijective swizzle: nwg % 8 == 0 for both gemms (1536, 512).
    int q = gridDim.x >> 3;
    int wg = (blockIdx.x & 7) * q + (blockIdx.x >> 3);
    int row0 = (wg & 63) * BM;        // M/BM = 64 for both gemms
    int col0 = (wg >> 6) * BM;

    // coalesced + chunk-XOR staging lane map (see header comment)
    int srow = lane >> 2;
    int scol = (((lane & 3) ^ ((lane >> 3) & 3))) * 8;

    // fragment read offset (elements): row l15, kg lg -> swizzled chunk
    int frag_off = l15 * 32 + ((lg ^ ((l15 >> 1) & 3)) * 8);

    f32x4 acc[4][4] = {};

    // stage tile t into slot: wave w supplies segments {w, w+4}; lane l's 16 B
    // land at seg_base + l*16.
    auto STAGE = [&](int t, int slot) {
#pragma unroll
        for (int i = 0; i < 2; i++) {
            int s = wid + i * 4;
            gload_lds16(A  + (size_t)(row0 + s * 16 + srow) * K + t * BK + scol, &As[slot][s * 512]);
            gload_lds16(Bt + (size_t)(col0 + s * 16 + srow) * K + t * BK + scol, &Bs[slot][s * 512]);
        }
    };

    STAGE(0, 0);
    STAGE(1, 1);

    for (int t = 0; t < KT; ++t) {
        int slot = t % 3;
        // Own-wave bound on tile t's 4 loads; barrier join makes all waves'
        // tile-t data visible after the barrier.
        if (t == KT - 1) asm volatile("s_waitcnt vmcnt(0)" ::: "memory");
        else             asm volatile("s_waitcnt vmcnt(4)" ::: "memory");
        __builtin_amdgcn_s_barrier();
        __builtin_amdgcn_sched_barrier(0);
        // ds_reads first: their lgkm latency hides under the STAGE VMEM issues.
        bf16x8 fa[4], fb[4];
#pragma unroll
        for (int m = 0; m < 4; m++)
            fa[m] = *(const bf16x8*)&As[slot][(wr * 4 + m) * 512 + frag_off];
#pragma unroll
        for (int n = 0; n < 4; n++)
            fb[n] = *(const bf16x8*)&Bs[slot][(wc * 4 + n) * 512 + frag_off];
        if (t + 2 < KT) STAGE(t + 2, (t + 2) % 3);
        __builtin_amdgcn_s_setprio(1);
#pragma unroll
        for (int m = 0; m < 4; m++)
#pragma unroll
            for (int n = 0; n < 4; n++)
                acc[m][n] = __builtin_amdgcn_mfma_f32_16x16x32_bf16(fa[m], fb[n], acc[m][n], 0, 0, 0);
        __builtin_amdgcn_s_setprio(0);
    }

#pragma unroll
    for (int m = 0; m < 4; m++) {
#pragma unroll
        for (int n = 0; n < 4; n++) {
            int col = col0 + wc * 64 + n * 16 + l15;
#pragma unroll
            for (int r = 0; r < 4; r++) {
                int row = row0 + wr * 64 + m * 16 + lg * 4 + r;
                float v = acc[m][n][r];
                if (MODE == 0) {
                    v += pos[((row & 1023) << 10) + (col & 1023)];
                    Cbf[(size_t)row * Ncols + col] = (__bf16)v;
                } else {
                    corr[(size_t)row * 1024 + col] = v;
                }
            }
        }
    }
}

// ---------------------------------------------------------------------------
// Kernel 4: windowed attention. One wave per (b, n). QKV row = Q|K|V bf16.
// scores over 9 clipped neighbors, softmax in-register, ctx written bf16.
// ---------------------------------------------------------------------------
__global__ __launch_bounds__(256) void attn_kernel(const __bf16* __restrict__ QKV,
                                                   __bf16* __restrict__ ctx) {
    int wg   = blockIdx.x * 4 + (threadIdx.x >> 6);  // = b*1024 + n
    int lane = threadIdx.x & 63;
    int n = wg & 1023;
    int browbase = wg - n;  // b*1024

    const __bf16* qrow = QKV + (size_t)wg * N3_;
    bf16x8 q0 = *(const bf16x8*)(qrow + lane * 8);
    bf16x8 q1 = *(const bf16x8*)(qrow + 512 + lane * 8);
    float qf[16];
#pragma unroll
    for (int i = 0; i < 8; i++) { qf[i] = (float)q0[i]; qf[8 + i] = (float)q1[i]; }

    float sc[WIN_];
#pragma unroll
    for (int w = 0; w < WIN_; w++) {
        int nn = n - HALF_ + w;
        nn = (nn < 0) ? 0 : (nn > 1023 ? 1023 : nn);
        const __bf16* krow = QKV + (size_t)(browbase + nn) * N3_ + D_;
        bf16x8 k0 = *(const bf16x8*)(krow + lane * 8);
        bf16x8 k1 = *(const bf16x8*)(krow + 512 + lane * 8);
        float s = 0.f;
#pragma unroll
        for (int i = 0; i < 8; i++)
            s += qf[i] * (float)k0[i] + qf[8 + i] * (float)k1[i];
        s += __shfl_xor(s, 32); s += __shfl_xor(s, 16); s += __shfl_xor(s, 8);
        s += __shfl_xor(s, 4);  s += __shfl_xor(s, 2);  s += __shfl_xor(s, 1);
        sc[w] = s * 0.03125f;  // 1/sqrt(1024)
    }

    float mx = sc[0];
#pragma unroll
    for (int w = 1; w < WIN_; w++) mx = fmaxf(mx, sc[w]);
    float e[WIN_], sum = 0.f;
#pragma unroll
    for (int w = 0; w < WIN_; w++) { e[w] = __expf(sc[w] - mx); sum += e[w]; }
    float inv = 1.0f / sum;

    float accv[16];
#pragma unroll
    for (int i = 0; i < 16; i++) accv[i] = 0.f;
#pragma unroll
    for (int w = 0; w < WIN_; w++) {
        int nn = n - HALF_ + w;
        nn = (nn < 0) ? 0 : (nn > 1023 ? 1023 : nn);
        const __bf16* vrow = QKV + (size_t)(browbase + nn) * N3_ + 2 * D_;
        bf16x8 v0 = *(const bf16x8*)(vrow + lane * 8);
        bf16x8 v1 = *(const bf16x8*)(vrow + 512 + lane * 8);
        float aw = e[w] * inv;
#pragma unroll
        for (int i = 0; i < 8; i++) {
            accv[i]     += aw * (float)v0[i];
            accv[8 + i] += aw * (float)v1[i];
        }
    }

    bf16x8 o0, o1;
#pragma unroll
    for (int i = 0; i < 8; i++) { o0[i] = (__bf16)accv[i]; o1[i] = (__bf16)accv[8 + i]; }
    __bf16* crow = ctx + (size_t)wg * D_;
    *(bf16x8*)(crow + lane * 8) = o0;
    *(bf16x8*)(crow + 512 + lane * 8) = o1;
}

// ---------------------------------------------------------------------------
// Kernel 6: out[rc, t] = xb[rc, t] + corr[rc], flat float4 grid-stride.
// Nontemporal on the pure streams (xb, out); corr stays cached.
// ---------------------------------------------------------------------------
__global__ __launch_bounds__(256) void add_kernel(const float* __restrict__ xb,
                                                  const float* __restrict__ corr,
                                                  float* __restrict__ outp) {
    const long long total4 = (long long)M_ * C_ * T_ / 4;   // 67,108,864
    long long stride = (long long)gridDim.x * 256;
#pragma unroll 4
    for (long long i = (long long)blockIdx.x * 256 + threadIdx.x; i < total4; i += stride) {
        float c = corr[i >> 3];                 // 8 lanes share one corr value
        f32x4 x = __builtin_nontemporal_load((const f32x4*)xb + i);
        x.x += c; x.y += c; x.z += c; x.w += c;
        __builtin_nontemporal_store(x, (f32x4*)outp + i);
    }
}

// ---------------------------------------------------------------------------
extern "C" void kernel_launch(void* const* d_in, const int* in_sizes, int n_in,
                              void* d_out, int out_size, void* d_ws, size_t ws_size,
                              hipStream_t stream) {
    const float* xb  = (const float*)d_in[0];
    const float* Wq  = (const float*)d_in[1];
    const float* Wk  = (const float*)d_in[2];
    const float* Wv  = (const float*)d_in[3];
    const float* Wo  = (const float*)d_in[4];
    const float* pos = (const float*)d_in[5];
    float* out = (float*)d_out;

    char* ws = (char*)d_ws;
    // workspace layout (bytes)
    __bf16* tokens = (__bf16*)(ws);                       // M*1024*2      = 16 MB
    __bf16* wqkvt  = (__bf16*)(ws + 16777216);            // 3072*1024*2   = 6 MB
    __bf16* wot    = (__bf16*)(ws + 23068672);            // 1024*1024*2   = 2 MB
    __bf16* qkv    = (__bf16*)(ws + 25165824);            // M*3072*2      = 48 MB
    __bf16* ctx    = (__bf16*)(ws + 75497472);            // M*1024*2      = 16 MB
    float*  corr   = (float*)(ws + 25165824);             // reuse qkv: M*1024*4 = 32 MB
    // total 88 MB

    // 1. tokens = mean(xb, T)   (grid-stride, 2048 blocks)
    mean_kernel<<<dim3(2048), dim3(256), 0, stream>>>(xb, tokens);

    // 2. weight transpose + bf16 cast
    transpose_kernel<<<dim3(32, 32, 4), dim3(32, 8), 0, stream>>>(Wq, Wk, Wv, Wo, wqkvt, wot);

    // 3. QKV = tokens @ [Wq|Wk|Wv] + pos   (grid flattened 1D: 64 x 24 = 1536)
    gemm_kernel<0><<<dim3(1536), dim3(256), 0, stream>>>(
        tokens, wqkvt, 1024, N3_, pos, qkv, nullptr);

    // 4. windowed attention -> ctx
    attn_kernel<<<dim3(M_ / 4), dim3(256), 0, stream>>>(qkv, ctx);

    // 5. corr = ctx @ Wo  (fp32, 32 MB; overwrites dead qkv region; 64 x 8 = 512)
    gemm_kernel<1><<<dim3(512), dim3(256), 0, stream>>>(
        ctx, wot, 1024, C_, nullptr, nullptr, corr);

    // 6. out = xb + corr (broadcast over T)  (8192 blocks for TLP)
    add_kernel<<<dim3(8192), dim3(256), 0, stream>>>(xb, corr, out);
}

// Round 9
// 747.425 us; speedup vs baseline: 1.0292x; 1.0065x over previous
//
#include <hip/hip_runtime.h>

typedef __bf16 bf16x8 __attribute__((ext_vector_type(8)));
typedef float  f32x4  __attribute__((ext_vector_type(4)));

#define B_    8
#define NB_   1024
#define C_    1024
#define T_    32
#define D_    1024
#define M_    (B_ * NB_)      // 8192
#define N3_   (3 * D_)        // 3072
#define WIN_  9
#define HALF_ 4

// Async global->LDS, 16 B per lane. LDS dest is wave-uniform base; HW writes
// lane l at base + l*16. AS casts via integer round-trip.
__device__ __forceinline__ void gload_lds16(const void* g, void* l) {
    __builtin_amdgcn_global_load_lds(
        (const __attribute__((address_space(1))) void*)(unsigned long long)(uintptr_t)g,
        (__attribute__((address_space(3))) void*)(unsigned int)(uintptr_t)l,
        16, 0, 0);
}

// ---------------------------------------------------------------------------
// Kernel 1: tokens = mean(xb, axis=-1), cast to bf16.
// Grid-stride, 3072 blocks. 8 lanes per output; 1 KB contiguous per wave-iter.
// ---------------------------------------------------------------------------
__global__ __launch_bounds__(256) void mean_kernel(const float* __restrict__ xb,
                                                   __bf16* __restrict__ tok) {
    const int OUT = M_ * C_;                    // 8,388,608 outputs
    int lane  = threadIdx.x & 63;
    int chunk = lane & 7;
    int sub   = lane >> 3;                      // 0..7: output within wave-iter
    int gw = (blockIdx.x * 256 + threadIdx.x) >> 6;   // global wave id
    int nw = (gridDim.x * 256) >> 6;                  // total waves
    for (int o8 = gw * 8; o8 < OUT; o8 += nw * 8) {
        int o = o8 + sub;
        const f32x4* p = (const f32x4*)(xb + (size_t)o * T_ + chunk * 4);
        f32x4 v = __builtin_nontemporal_load(p);
        float s = v.x + v.y + v.z + v.w;
        s += __shfl_xor(s, 1);
        s += __shfl_xor(s, 2);
        s += __shfl_xor(s, 4);
        if (chunk == 0) tok[o] = (__bf16)(s * (1.0f / 32.0f));
    }
}

// ---------------------------------------------------------------------------
// Kernel 2: transpose W (K x N fp32) -> Wt (N x K bf16). 4 matrices:
// z=0..2 -> Wq,Wk,Wv into Wqkvt (3072 x 1024); z=3 -> Wo into Wot.
// ---------------------------------------------------------------------------
__global__ __launch_bounds__(256) void transpose_kernel(
    const float* __restrict__ Wq, const float* __restrict__ Wk,
    const float* __restrict__ Wv, const float* __restrict__ Wo,
    __bf16* __restrict__ Wqkvt, __bf16* __restrict__ Wot) {
    __shared__ float tile[32][33];
    int mat = blockIdx.z;
    const float* src = (mat == 0) ? Wq : (mat == 1) ? Wk : (mat == 2) ? Wv : Wo;
    __bf16* dst = (mat < 3) ? (Wqkvt + (size_t)mat * 1024 * 1024) : Wot;
    int tx = threadIdx.x, ty = threadIdx.y;
    int x  = blockIdx.x * 32 + tx;   // source col (n)
    int y0 = blockIdx.y * 32;        // source row base (k)
#pragma unroll
    for (int j = 0; j < 32; j += 8)
        tile[ty + j][tx] = src[(size_t)(y0 + ty + j) * 1024 + x];
    __syncthreads();
    int k = y0 + tx;
#pragma unroll
    for (int j = 0; j < 32; j += 8) {
        int n = blockIdx.x * 32 + ty + j;
        dst[(size_t)n * 1024 + k] = (__bf16)tile[tx][ty + j];
    }
}

// ---------------------------------------------------------------------------
// Kernel 3/5: bf16 MFMA GEMM — R5 configuration verbatim (empirical winner:
// 731 µs total; R6 geometry / R7 layout / R8 swizzle all regressed).
// 128x128 tile, BK=32, KT=32, 4 waves (2x2), wave 64x64 = 4x4 frags of
// 16x16x32. Linear row-major [128][32] LDS; staging srow=lane>>2 (4 lanes
// per 64 B row strip, fully coalesced); fragment ds_read_b128 at 64 B row
// stride = uniform 8 accesses/bank = the b128 minimum (aggregate
// conflict-free; verified empirically vs k-group-major and XOR variants).
// Per iter: vmcnt(4) -> s_barrier -> ds_read t -> stage t+2 -> setprio MFMA.
// Loads never drain to 0 in steady state (T4). XCD-bijective swizzle (T1).
// MODE 0: C += pos (broadcast over b), write bf16 (QKV).
// MODE 1: write fp32 correction matrix corr[row, col].
// ---------------------------------------------------------------------------
template <int MODE>
__global__ __launch_bounds__(256) void gemm_kernel(
    const __bf16* __restrict__ A, const __bf16* __restrict__ Bt,
    int K, int Ncols,
    const float* __restrict__ pos, __bf16* __restrict__ Cbf,
    float* __restrict__ corr) {
    constexpr int BM = 128, BK = 32, KT = 32;   // K = 1024 fixed
    __shared__ __align__(16) __bf16 As[3][BM * BK];   // 3 x 8 KB
    __shared__ __align__(16) __bf16 Bs[3][BM * BK];   // 3 x 8 KB
    int tid = threadIdx.x;
    int wid = tid >> 6, lane = tid & 63;
    int wr = wid >> 1, wc = wid & 1;
    int l15 = lane & 15, lg = lane >> 4;

    // XCD-bijective swizzle: nwg % 8 == 0 for both gemms (1536, 512).
    int q = gridDim.x >> 3;
    int wg = (blockIdx.x & 7) * q + (blockIdx.x >> 3);
    int row0 = (wg & 63) * BM;        // M/BM = 64 for both gemms
    int col0 = (wg >> 6) * BM;

    int srow = lane >> 2;
    int scol = (lane & 3) * 8;

    f32x4 acc[4][4] = {};

    // stage tile t into slot: wave w supplies segments {w, w+4}; lane l's 16 B
    // land at seg_base + l*16 = row-major [16][32] chunk.
    auto STAGE = [&](int t, int slot) {
#pragma unroll
        for (int i = 0; i < 2; i++) {
            int s = wid + i * 4;
            gload_lds16(A  + (size_t)(row0 + s * 16 + srow) * K + t * BK + scol, &As[slot][s * 512]);
            gload_lds16(Bt + (size_t)(col0 + s * 16 + srow) * K + t * BK + scol, &Bs[slot][s * 512]);
        }
    };

    STAGE(0, 0);
    STAGE(1, 1);

    for (int t = 0; t < KT; ++t) {
        int slot = t % 3;
        // Own-wave bound on tile t's 4 loads; barrier join makes all waves'
        // tile-t data visible after the barrier.
        if (t == KT - 1) asm volatile("s_waitcnt vmcnt(0)" ::: "memory");
        else             asm volatile("s_waitcnt vmcnt(4)" ::: "memory");
        __builtin_amdgcn_s_barrier();
        __builtin_amdgcn_sched_barrier(0);
        // ds_reads first: their lgkm latency hides under the STAGE VMEM issues.
        bf16x8 fa[4], fb[4];
#pragma unroll
        for (int m = 0; m < 4; m++)
            fa[m] = *(const bf16x8*)&As[slot][(wr * 64 + m * 16 + l15) * BK + lg * 8];
#pragma unroll
        for (int n = 0; n < 4; n++)
            fb[n] = *(const bf16x8*)&Bs[slot][(wc * 64 + n * 16 + l15) * BK + lg * 8];
        if (t + 2 < KT) STAGE(t + 2, (t + 2) % 3);
        __builtin_amdgcn_s_setprio(1);
#pragma unroll
        for (int m = 0; m < 4; m++)
#pragma unroll
            for (int n = 0; n < 4; n++)
                acc[m][n] = __builtin_amdgcn_mfma_f32_16x16x32_bf16(fa[m], fb[n], acc[m][n], 0, 0, 0);
        __builtin_amdgcn_s_setprio(0);
    }

#pragma unroll
    for (int m = 0; m < 4; m++) {
#pragma unroll
        for (int n = 0; n < 4; n++) {
            int col = col0 + wc * 64 + n * 16 + l15;
#pragma unroll
            for (int r = 0; r < 4; r++) {
                int row = row0 + wr * 64 + m * 16 + lg * 4 + r;
                float v = acc[m][n][r];
                if (MODE == 0) {
                    v += pos[((row & 1023) << 10) + (col & 1023)];
                    Cbf[(size_t)row * Ncols + col] = (__bf16)v;
                } else {
                    corr[(size_t)row * 1024 + col] = v;
                }
            }
        }
    }
}

// ---------------------------------------------------------------------------
// Kernel 4: windowed attention. One wave per (b, n). QKV row = Q|K|V bf16.
// scores over 9 clipped neighbors, softmax in-register, ctx written bf16.
// ---------------------------------------------------------------------------
__global__ __launch_bounds__(256) void attn_kernel(const __bf16* __restrict__ QKV,
                                                   __bf16* __restrict__ ctx) {
    int wg   = blockIdx.x * 4 + (threadIdx.x >> 6);  // = b*1024 + n
    int lane = threadIdx.x & 63;
    int n = wg & 1023;
    int browbase = wg - n;  // b*1024

    const __bf16* qrow = QKV + (size_t)wg * N3_;
    bf16x8 q0 = *(const bf16x8*)(qrow + lane * 8);
    bf16x8 q1 = *(const bf16x8*)(qrow + 512 + lane * 8);
    float qf[16];
#pragma unroll
    for (int i = 0; i < 8; i++) { qf[i] = (float)q0[i]; qf[8 + i] = (float)q1[i]; }

    float sc[WIN_];
#pragma unroll
    for (int w = 0; w < WIN_; w++) {
        int nn = n - HALF_ + w;
        nn = (nn < 0) ? 0 : (nn > 1023 ? 1023 : nn);
        const __bf16* krow = QKV + (size_t)(browbase + nn) * N3_ + D_;
        bf16x8 k0 = *(const bf16x8*)(krow + lane * 8);
        bf16x8 k1 = *(const bf16x8*)(krow + 512 + lane * 8);
        float s = 0.f;
#pragma unroll
        for (int i = 0; i < 8; i++)
            s += qf[i] * (float)k0[i] + qf[8 + i] * (float)k1[i];
        s += __shfl_xor(s, 32); s += __shfl_xor(s, 16); s += __shfl_xor(s, 8);
        s += __shfl_xor(s, 4);  s += __shfl_xor(s, 2);  s += __shfl_xor(s, 1);
        sc[w] = s * 0.03125f;  // 1/sqrt(1024)
    }

    float mx = sc[0];
#pragma unroll
    for (int w = 1; w < WIN_; w++) mx = fmaxf(mx, sc[w]);
    float e[WIN_], sum = 0.f;
#pragma unroll
    for (int w = 0; w < WIN_; w++) { e[w] = __expf(sc[w] - mx); sum += e[w]; }
    float inv = 1.0f / sum;

    float accv[16];
#pragma unroll
    for (int i = 0; i < 16; i++) accv[i] = 0.f;
#pragma unroll
    for (int w = 0; w < WIN_; w++) {
        int nn = n - HALF_ + w;
        nn = (nn < 0) ? 0 : (nn > 1023 ? 1023 : nn);
        const __bf16* vrow = QKV + (size_t)(browbase + nn) * N3_ + 2 * D_;
        bf16x8 v0 = *(const bf16x8*)(vrow + lane * 8);
        bf16x8 v1 = *(const bf16x8*)(vrow + 512 + lane * 8);
        float aw = e[w] * inv;
#pragma unroll
        for (int i = 0; i < 8; i++) {
            accv[i]     += aw * (float)v0[i];
            accv[8 + i] += aw * (float)v1[i];
        }
    }

    bf16x8 o0, o1;
#pragma unroll
    for (int i = 0; i < 8; i++) { o0[i] = (__bf16)accv[i]; o1[i] = (__bf16)accv[8 + i]; }
    __bf16* crow = ctx + (size_t)wg * D_;
    *(bf16x8*)(crow + lane * 8) = o0;
    *(bf16x8*)(crow + 512 + lane * 8) = o1;
}

// ---------------------------------------------------------------------------
// Kernel 6: out[rc, t] = xb[rc, t] + corr[rc], flat float4 grid-stride.
// Nontemporal on the pure streams (xb, out); corr stays cached.
// ---------------------------------------------------------------------------
__global__ __launch_bounds__(256) void add_kernel(const float* __restrict__ xb,
                                                  const float* __restrict__ corr,
                                                  float* __restrict__ outp) {
    const long long total4 = (long long)M_ * C_ * T_ / 4;   // 67,108,864
    long long stride = (long long)gridDim.x * 256;
#pragma unroll 4
    for (long long i = (long long)blockIdx.x * 256 + threadIdx.x; i < total4; i += stride) {
        float c = corr[i >> 3];                 // 8 lanes share one corr value
        f32x4 x = __builtin_nontemporal_load((const f32x4*)xb + i);
        x.x += c; x.y += c; x.z += c; x.w += c;
        __builtin_nontemporal_store(x, (f32x4*)outp + i);
    }
}

// ---------------------------------------------------------------------------
extern "C" void kernel_launch(void* const* d_in, const int* in_sizes, int n_in,
                              void* d_out, int out_size, void* d_ws, size_t ws_size,
                              hipStream_t stream) {
    const float* xb  = (const float*)d_in[0];
    const float* Wq  = (const float*)d_in[1];
    const float* Wk  = (const float*)d_in[2];
    const float* Wv  = (const float*)d_in[3];
    const float* Wo  = (const float*)d_in[4];
    const float* pos = (const float*)d_in[5];
    float* out = (float*)d_out;

    char* ws = (char*)d_ws;
    // workspace layout (bytes)
    __bf16* tokens = (__bf16*)(ws);                       // M*1024*2      = 16 MB
    __bf16* wqkvt  = (__bf16*)(ws + 16777216);            // 3072*1024*2   = 6 MB
    __bf16* wot    = (__bf16*)(ws + 23068672);            // 1024*1024*2   = 2 MB
    __bf16* qkv    = (__bf16*)(ws + 25165824);            // M*3072*2      = 48 MB
    __bf16* ctx    = (__bf16*)(ws + 75497472);            // M*1024*2      = 16 MB
    float*  corr   = (float*)(ws + 25165824);             // reuse qkv: M*1024*4 = 32 MB
    // total 88 MB

    // 1. tokens = mean(xb, T)   (grid-stride, 3072 blocks)
    mean_kernel<<<dim3(3072), dim3(256), 0, stream>>>(xb, tokens);

    // 2. weight transpose + bf16 cast
    transpose_kernel<<<dim3(32, 32, 4), dim3(32, 8), 0, stream>>>(Wq, Wk, Wv, Wo, wqkvt, wot);

    // 3. QKV = tokens @ [Wq|Wk|Wv] + pos   (grid flattened 1D: 64 x 24 = 1536)
    gemm_kernel<0><<<dim3(1536), dim3(256), 0, stream>>>(
        tokens, wqkvt, 1024, N3_, pos, qkv, nullptr);

    // 4. windowed attention -> ctx
    attn_kernel<<<dim3(M_ / 4), dim3(256), 0, stream>>>(qkv, ctx);

    // 5. corr = ctx @ Wo  (fp32, 32 MB; overwrites dead qkv region; 64 x 8 = 512)
    gemm_kernel<1><<<dim3(512), dim3(256), 0, stream>>>(
        ctx, wot, 1024, C_, nullptr, nullptr, corr);

    // 6. out = xb + corr (broadcast over T)  (12288 blocks for TLP)
    add_kernel<<<dim3(12288), dim3(256), 0, stream>>>(xb, corr, out);
}

// Round 10
// 746.413 us; speedup vs baseline: 1.0306x; 1.0014x over previous
//
#include <hip/hip_runtime.h>

typedef __bf16 bf16x8 __attribute__((ext_vector_type(8)));
typedef float  f32x4  __attribute__((ext_vector_type(4)));

#define B_    8
#define NB_   1024
#define C_    1024
#define T_    32
#define D_    1024
#define M_    (B_ * NB_)      // 8192
#define N3_   (3 * D_)        // 3072
#define WIN_  9
#define HALF_ 4

// Async global->LDS, 16 B per lane. LDS dest is wave-uniform base; HW writes
// lane l at base + l*16. AS casts via integer round-trip.
__device__ __forceinline__ void gload_lds16(const void* g, void* l) {
    __builtin_amdgcn_global_load_lds(
        (const __attribute__((address_space(1))) void*)(unsigned long long)(uintptr_t)g,
        (__attribute__((address_space(3))) void*)(unsigned int)(uintptr_t)l,
        16, 0, 0);
}

// ---------------------------------------------------------------------------
// Kernel 1: tokens = mean(xb, axis=-1), cast to bf16.
// Grid-stride, 2048 blocks (R5 winner). 8 lanes per output.
// ---------------------------------------------------------------------------
__global__ __launch_bounds__(256) void mean_kernel(const float* __restrict__ xb,
                                                   __bf16* __restrict__ tok) {
    const int OUT = M_ * C_;                    // 8,388,608 outputs
    int lane  = threadIdx.x & 63;
    int chunk = lane & 7;
    int sub   = lane >> 3;                      // 0..7: output within wave-iter
    int gw = (blockIdx.x * 256 + threadIdx.x) >> 6;   // global wave id
    int nw = (gridDim.x * 256) >> 6;                  // total waves
    for (int o8 = gw * 8; o8 < OUT; o8 += nw * 8) {
        int o = o8 + sub;
        const f32x4* p = (const f32x4*)(xb + (size_t)o * T_ + chunk * 4);
        f32x4 v = __builtin_nontemporal_load(p);
        float s = v.x + v.y + v.z + v.w;
        s += __shfl_xor(s, 1);
        s += __shfl_xor(s, 2);
        s += __shfl_xor(s, 4);
        if (chunk == 0) tok[o] = (__bf16)(s * (1.0f / 32.0f));
    }
}

// ---------------------------------------------------------------------------
// Kernel 2: transpose W (K x N fp32) -> Wt (N x K bf16). 4 matrices:
// z=0..2 -> Wq,Wk,Wv into Wqkvt (3072 x 1024); z=3 -> Wo into Wot.
// ---------------------------------------------------------------------------
__global__ __launch_bounds__(256) void transpose_kernel(
    const float* __restrict__ Wq, const float* __restrict__ Wk,
    const float* __restrict__ Wv, const float* __restrict__ Wo,
    __bf16* __restrict__ Wqkvt, __bf16* __restrict__ Wot) {
    __shared__ float tile[32][33];
    int mat = blockIdx.z;
    const float* src = (mat == 0) ? Wq : (mat == 1) ? Wk : (mat == 2) ? Wv : Wo;
    __bf16* dst = (mat < 3) ? (Wqkvt + (size_t)mat * 1024 * 1024) : Wot;
    int tx = threadIdx.x, ty = threadIdx.y;
    int x  = blockIdx.x * 32 + tx;   // source col (n)
    int y0 = blockIdx.y * 32;        // source row base (k)
#pragma unroll
    for (int j = 0; j < 32; j += 8)
        tile[ty + j][tx] = src[(size_t)(y0 + ty + j) * 1024 + x];
    __syncthreads();
    int k = y0 + tx;
#pragma unroll
    for (int j = 0; j < 32; j += 8) {
        int n = blockIdx.x * 32 + ty + j;
        dst[(size_t)n * 1024 + k] = (__bf16)tile[tx][ty + j];
    }
}

// ---------------------------------------------------------------------------
// Kernel 3/5: bf16 MFMA GEMM — R5 sync structure verbatim (empirical winner).
// 128x128 tile, BK=32, KT=32, 4 waves (2x2), wave 64x64 = 4x4 frags of
// 16x16x32. Linear row-major [128][32] LDS; per iter: vmcnt(4) -> s_barrier
// -> ds_read t -> stage t+2 -> setprio MFMA. XCD-bijective swizzle (T1).
// MODE 0: C += pos, write bf16 qkv via LDS-transposed COALESCED epilogue
//   (64 scalar 2-B stores -> 8x dwordx4 per wave; As[0] reused race-free:
//   last iter reads slot 1, barrier(t=31) drains all slot-0 reads).
// MODE 1: write fp32 corr (already 64-B-chunked, direct stores kept).
// ---------------------------------------------------------------------------
template <int MODE>
__global__ __launch_bounds__(256) void gemm_kernel(
    const __bf16* __restrict__ A, const __bf16* __restrict__ Bt,
    int K, int Ncols,
    const float* __restrict__ pos, __bf16* __restrict__ Cbf,
    float* __restrict__ corr) {
    constexpr int BM = 128, BK = 32, KT = 32;   // K = 1024 fixed
    __shared__ __align__(16) __bf16 As[3][BM * BK];   // 3 x 8 KB
    __shared__ __align__(16) __bf16 Bs[3][BM * BK];   // 3 x 8 KB
    int tid = threadIdx.x;
    int wid = tid >> 6, lane = tid & 63;
    int wr = wid >> 1, wc = wid & 1;
    int l15 = lane & 15, lg = lane >> 4;

    // XCD-bijective swizzle: nwg % 8 == 0 for both gemms (1536, 512).
    int q = gridDim.x >> 3;
    int wg = (blockIdx.x & 7) * q + (blockIdx.x >> 3);
    int row0 = (wg & 63) * BM;        // M/BM = 64 for both gemms
    int col0 = (wg >> 6) * BM;

    int srow = lane >> 2;
    int scol = (lane & 3) * 8;

    f32x4 acc[4][4] = {};

    // stage tile t into slot: wave w supplies segments {w, w+4}; lane l's 16 B
    // land at seg_base + l*16 = row-major [16][32] chunk.
    auto STAGE = [&](int t, int slot) {
#pragma unroll
        for (int i = 0; i < 2; i++) {
            int s = wid + i * 4;
            gload_lds16(A  + (size_t)(row0 + s * 16 + srow) * K + t * BK + scol, &As[slot][s * 512]);
            gload_lds16(Bt + (size_t)(col0 + s * 16 + srow) * K + t * BK + scol, &Bs[slot][s * 512]);
        }
    };

    STAGE(0, 0);
    STAGE(1, 1);

    for (int t = 0; t < KT; ++t) {
        int slot = t % 3;
        // Own-wave bound on tile t's 4 loads; barrier join makes all waves'
        // tile-t data visible after the barrier.
        if (t == KT - 1) asm volatile("s_waitcnt vmcnt(0)" ::: "memory");
        else             asm volatile("s_waitcnt vmcnt(4)" ::: "memory");
        __builtin_amdgcn_s_barrier();
        __builtin_amdgcn_sched_barrier(0);
        // ds_reads first: their lgkm latency hides under the STAGE VMEM issues.
        bf16x8 fa[4], fb[4];
#pragma unroll
        for (int m = 0; m < 4; m++)
            fa[m] = *(const bf16x8*)&As[slot][(wr * 64 + m * 16 + l15) * BK + lg * 8];
#pragma unroll
        for (int n = 0; n < 4; n++)
            fb[n] = *(const bf16x8*)&Bs[slot][(wc * 64 + n * 16 + l15) * BK + lg * 8];
        if (t + 2 < KT) STAGE(t + 2, (t + 2) % 3);
        __builtin_amdgcn_s_setprio(1);
#pragma unroll
        for (int m = 0; m < 4; m++)
#pragma unroll
            for (int n = 0; n < 4; n++)
                acc[m][n] = __builtin_amdgcn_mfma_f32_16x16x32_bf16(fa[m], fb[n], acc[m][n], 0, 0, 0);
        __builtin_amdgcn_s_setprio(0);
    }

    if (MODE == 0) {
        // Coalesced epilogue: per wave, 2 KB private LDS strip in As[0].
        __bf16* stg = &As[0][wid * 1024];   // [16 rows][64 cols] bf16
        int rsub = lane >> 3;               // 0..7
        int csub = lane & 7;                // 0..7 (16-B chunk)
#pragma unroll
        for (int m = 0; m < 4; m++) {
            // stage frag m (rows m*16+lg*4+r, cols n*16+l15) with pos added
#pragma unroll
            for (int n = 0; n < 4; n++) {
                int col = col0 + wc * 64 + n * 16 + l15;
#pragma unroll
                for (int r = 0; r < 4; r++) {
                    int row = row0 + wr * 64 + m * 16 + lg * 4 + r;
                    float v = acc[m][n][r] + pos[((row & 1023) << 10) + (col & 1023)];
                    stg[(lg * 4 + r) * 64 + n * 16 + l15] = (__bf16)v;
                }
            }
            // wave-local ds_write -> ds_read ordering handled by compiler
#pragma unroll
            for (int h = 0; h < 2; h++) {
                int lrow = h * 8 + rsub;
                bf16x8 vv = *(const bf16x8*)&stg[lrow * 64 + csub * 8];
                int grow = row0 + wr * 64 + m * 16 + lrow;
                *(bf16x8*)&Cbf[(size_t)grow * Ncols + col0 + wc * 64 + csub * 8] = vv;
            }
        }
    } else {
#pragma unroll
        for (int m = 0; m < 4; m++) {
#pragma unroll
            for (int n = 0; n < 4; n++) {
                int col = col0 + wc * 64 + n * 16 + l15;
#pragma unroll
                for (int r = 0; r < 4; r++) {
                    int row = row0 + wr * 64 + m * 16 + lg * 4 + r;
                    corr[(size_t)row * 1024 + col] = acc[m][n][r];
                }
            }
        }
    }
}

// ---------------------------------------------------------------------------
// Kernel 4: windowed attention. One wave per (b, n). QKV row = Q|K|V bf16.
// scores over 9 clipped neighbors, softmax in-register, ctx written bf16.
// ---------------------------------------------------------------------------
__global__ __launch_bounds__(256) void attn_kernel(const __bf16* __restrict__ QKV,
                                                   __bf16* __restrict__ ctx) {
    int wg   = blockIdx.x * 4 + (threadIdx.x >> 6);  // = b*1024 + n
    int lane = threadIdx.x & 63;
    int n = wg & 1023;
    int browbase = wg - n;  // b*1024

    const __bf16* qrow = QKV + (size_t)wg * N3_;
    bf16x8 q0 = *(const bf16x8*)(qrow + lane * 8);
    bf16x8 q1 = *(const bf16x8*)(qrow + 512 + lane * 8);
    float qf[16];
#pragma unroll
    for (int i = 0; i < 8; i++) { qf[i] = (float)q0[i]; qf[8 + i] = (float)q1[i]; }

    float sc[WIN_];
#pragma unroll
    for (int w = 0; w < WIN_; w++) {
        int nn = n - HALF_ + w;
        nn = (nn < 0) ? 0 : (nn > 1023 ? 1023 : nn);
        const __bf16* krow = QKV + (size_t)(browbase + nn) * N3_ + D_;
        bf16x8 k0 = *(const bf16x8*)(krow + lane * 8);
        bf16x8 k1 = *(const bf16x8*)(krow + 512 + lane * 8);
        float s = 0.f;
#pragma unroll
        for (int i = 0; i < 8; i++)
            s += qf[i] * (float)k0[i] + qf[8 + i] * (float)k1[i];
        s += __shfl_xor(s, 32); s += __shfl_xor(s, 16); s += __shfl_xor(s, 8);
        s += __shfl_xor(s, 4);  s += __shfl_xor(s, 2);  s += __shfl_xor(s, 1);
        sc[w] = s * 0.03125f;  // 1/sqrt(1024)
    }

    float mx = sc[0];
#pragma unroll
    for (int w = 1; w < WIN_; w++) mx = fmaxf(mx, sc[w]);
    float e[WIN_], sum = 0.f;
#pragma unroll
    for (int w = 0; w < WIN_; w++) { e[w] = __expf(sc[w] - mx); sum += e[w]; }
    float inv = 1.0f / sum;

    float accv[16];
#pragma unroll
    for (int i = 0; i < 16; i++) accv[i] = 0.f;
#pragma unroll
    for (int w = 0; w < WIN_; w++) {
        int nn = n - HALF_ + w;
        nn = (nn < 0) ? 0 : (nn > 1023 ? 1023 : nn);
        const __bf16* vrow = QKV + (size_t)(browbase + nn) * N3_ + 2 * D_;
        bf16x8 v0 = *(const bf16x8*)(vrow + lane * 8);
        bf16x8 v1 = *(const bf16x8*)(vrow + 512 + lane * 8);
        float aw = e[w] * inv;
#pragma unroll
        for (int i = 0; i < 8; i++) {
            accv[i]     += aw * (float)v0[i];
            accv[8 + i] += aw * (float)v1[i];
        }
    }

    bf16x8 o0, o1;
#pragma unroll
    for (int i = 0; i < 8; i++) { o0[i] = (__bf16)accv[i]; o1[i] = (__bf16)accv[8 + i]; }
    __bf16* crow = ctx + (size_t)wg * D_;
    *(bf16x8*)(crow + lane * 8) = o0;
    *(bf16x8*)(crow + 512 + lane * 8) = o1;
}

// ---------------------------------------------------------------------------
// Kernel 6: out[rc, t] = xb[rc, t] + corr[rc], flat float4 grid-stride.
// Nontemporal on the pure streams (xb, out); corr stays cached.
// ---------------------------------------------------------------------------
__global__ __launch_bounds__(256) void add_kernel(const float* __restrict__ xb,
                                                  const float* __restrict__ corr,
                                                  float* __restrict__ outp) {
    const long long total4 = (long long)M_ * C_ * T_ / 4;   // 67,108,864
    long long stride = (long long)gridDim.x * 256;
#pragma unroll 4
    for (long long i = (long long)blockIdx.x * 256 + threadIdx.x; i < total4; i += stride) {
        float c = corr[i >> 3];                 // 8 lanes share one corr value
        f32x4 x = __builtin_nontemporal_load((const f32x4*)xb + i);
        x.x += c; x.y += c; x.z += c; x.w += c;
        __builtin_nontemporal_store(x, (f32x4*)outp + i);
    }
}

// ---------------------------------------------------------------------------
extern "C" void kernel_launch(void* const* d_in, const int* in_sizes, int n_in,
                              void* d_out, int out_size, void* d_ws, size_t ws_size,
                              hipStream_t stream) {
    const float* xb  = (const float*)d_in[0];
    const float* Wq  = (const float*)d_in[1];
    const float* Wk  = (const float*)d_in[2];
    const float* Wv  = (const float*)d_in[3];
    const float* Wo  = (const float*)d_in[4];
    const float* pos = (const float*)d_in[5];
    float* out = (float*)d_out;

    char* ws = (char*)d_ws;
    // workspace layout (bytes)
    __bf16* tokens = (__bf16*)(ws);                       // M*1024*2      = 16 MB
    __bf16* wqkvt  = (__bf16*)(ws + 16777216);            // 3072*1024*2   = 6 MB
    __bf16* wot    = (__bf16*)(ws + 23068672);            // 1024*1024*2   = 2 MB
    __bf16* qkv    = (__bf16*)(ws + 25165824);            // M*3072*2      = 48 MB
    __bf16* ctx    = (__bf16*)(ws + 75497472);            // M*1024*2      = 16 MB
    float*  corr   = (float*)(ws + 25165824);             // reuse qkv: M*1024*4 = 32 MB
    // total 88 MB

    // 1. tokens = mean(xb, T)   (grid-stride, 2048 blocks — R5 winner)
    mean_kernel<<<dim3(2048), dim3(256), 0, stream>>>(xb, tokens);

    // 2. weight transpose + bf16 cast
    transpose_kernel<<<dim3(32, 32, 4), dim3(32, 8), 0, stream>>>(Wq, Wk, Wv, Wo, wqkvt, wot);

    // 3. QKV = tokens @ [Wq|Wk|Wv] + pos   (grid flattened 1D: 64 x 24 = 1536)
    gemm_kernel<0><<<dim3(1536), dim3(256), 0, stream>>>(
        tokens, wqkvt, 1024, N3_, pos, qkv, nullptr);

    // 4. windowed attention -> ctx
    attn_kernel<<<dim3(M_ / 4), dim3(256), 0, stream>>>(qkv, ctx);

    // 5. corr = ctx @ Wo  (fp32, 32 MB; overwrites dead qkv region; 64 x 8 = 512)
    gemm_kernel<1><<<dim3(512), dim3(256), 0, stream>>>(
        ctx, wot, 1024, C_, nullptr, nullptr, corr);

    // 6. out = xb + corr (broadcast over T)  (8192 blocks — R5 winner)
    add_kernel<<<dim3(8192), dim3(256), 0, stream>>>(xb, corr, out);
}

// Round 11
// 727.539 us; speedup vs baseline: 1.0573x; 1.0259x over previous
//
#include <hip/hip_runtime.h>

typedef __bf16 bf16x8 __attribute__((ext_vector_type(8)));
typedef float  f32x4  __attribute__((ext_vector_type(4)));

#define B_    8
#define NB_   1024
#define C_    1024
#define T_    32
#define D_    1024
#define M_    (B_ * NB_)      // 8192
#define N3_   (3 * D_)        // 3072
#define WIN_  9
#define HALF_ 4

// Async global->LDS, 16 B per lane. LDS dest is wave-uniform base; HW writes
// lane l at base + l*16. AS casts via integer round-trip.
__device__ __forceinline__ void gload_lds16(const void* g, void* l) {
    __builtin_amdgcn_global_load_lds(
        (const __attribute__((address_space(1))) void*)(unsigned long long)(uintptr_t)g,
        (__attribute__((address_space(3))) void*)(unsigned int)(uintptr_t)l,
        16, 0, 0);
}

// ---------------------------------------------------------------------------
// Kernel 1: tokens = mean(xb, axis=-1), cast to bf16.
// Grid-stride, 2048 blocks. 8 lanes per output.
// ---------------------------------------------------------------------------
__global__ __launch_bounds__(256) void mean_kernel(const float* __restrict__ xb,
                                                   __bf16* __restrict__ tok) {
    const int OUT = M_ * C_;                    // 8,388,608 outputs
    int lane  = threadIdx.x & 63;
    int chunk = lane & 7;
    int sub   = lane >> 3;                      // 0..7: output within wave-iter
    int gw = (blockIdx.x * 256 + threadIdx.x) >> 6;   // global wave id
    int nw = (gridDim.x * 256) >> 6;                  // total waves
    for (int o8 = gw * 8; o8 < OUT; o8 += nw * 8) {
        int o = o8 + sub;
        const f32x4* p = (const f32x4*)(xb + (size_t)o * T_ + chunk * 4);
        f32x4 v = __builtin_nontemporal_load(p);
        float s = v.x + v.y + v.z + v.w;
        s += __shfl_xor(s, 1);
        s += __shfl_xor(s, 2);
        s += __shfl_xor(s, 4);
        if (chunk == 0) tok[o] = (__bf16)(s * (1.0f / 32.0f));
    }
}

// ---------------------------------------------------------------------------
// Kernel 2: transpose W (K x N fp32) -> Wt (N x K bf16). 4 matrices:
// z=0..2 -> Wq,Wk,Wv into Wqkvt (3072 x 1024); z=3 -> Wo into Wot.
// ---------------------------------------------------------------------------
__global__ __launch_bounds__(256) void transpose_kernel(
    const float* __restrict__ Wq, const float* __restrict__ Wk,
    const float* __restrict__ Wv, const float* __restrict__ Wo,
    __bf16* __restrict__ Wqkvt, __bf16* __restrict__ Wot) {
    __shared__ float tile[32][33];
    int mat = blockIdx.z;
    const float* src = (mat == 0) ? Wq : (mat == 1) ? Wk : (mat == 2) ? Wv : Wo;
    __bf16* dst = (mat < 3) ? (Wqkvt + (size_t)mat * 1024 * 1024) : Wot;
    int tx = threadIdx.x, ty = threadIdx.y;
    int x  = blockIdx.x * 32 + tx;   // source col (n)
    int y0 = blockIdx.y * 32;        // source row base (k)
#pragma unroll
    for (int j = 0; j < 32; j += 8)
        tile[ty + j][tx] = src[(size_t)(y0 + ty + j) * 1024 + x];
    __syncthreads();
    int k = y0 + tx;
#pragma unroll
    for (int j = 0; j < 32; j += 8) {
        int n = blockIdx.x * 32 + ty + j;
        dst[(size_t)n * 1024 + k] = (__bf16)tile[tx][ty + j];
    }
}

// ---------------------------------------------------------------------------
// Kernel 3/5: bf16 MFMA GEMM. R5's 3-slot counted-vmcnt single-barrier
// skeleton (verified 5 rounds), now at 256x128 block / 4 waves of 128x64
// (2x2 wave grid). Per-wave per K-step: 32 MFMA : 12 ds_read (vs 16:8 at
// 64x64 wave tiles) — 1.8x less LDS/issue overhead per MFMA. LDS = 3 slots
// x (256+128)x32x2B = 72 KB -> 2 blocks/CU retained (R6's occupancy
// mistake avoided). vmcnt(6): 6 gloads/tile (A:4, B:2), t+1's 6 in flight.
// MODE 0: C += pos, bf16 qkv via LDS-staged coalesced epilogue.
// MODE 1: fp32 corr direct (64-B chunks already).
// ---------------------------------------------------------------------------
template <int MODE>
__global__ __launch_bounds__(256, 2) void gemm_kernel(
    const __bf16* __restrict__ A, const __bf16* __restrict__ Bt,
    int K, int Ncols,
    const float* __restrict__ pos, __bf16* __restrict__ Cbf,
    float* __restrict__ corr) {
    constexpr int BMA = 256, BNB = 128, BK = 32, KT = 32;   // K = 1024 fixed
    __shared__ __align__(16) __bf16 As[3][BMA * BK];   // 3 x 16 KB
    __shared__ __align__(16) __bf16 Bs[3][BNB * BK];   // 3 x 8 KB
    int tid = threadIdx.x;
    int wid = tid >> 6, lane = tid & 63;
    int wr = wid >> 1, wc = wid & 1;    // wave tile: rows wr*128, cols wc*64
    int l15 = lane & 15, lg = lane >> 4;

    // XCD-bijective swizzle: nwg % 8 == 0 (768, 256).
    int q = gridDim.x >> 3;
    int wg = (blockIdx.x & 7) * q + (blockIdx.x >> 3);
    int row0 = (wg & 31) * BMA;       // M/256 = 32 row-tiles for both gemms
    int col0 = (wg >> 5) * BNB;

    int srow = lane >> 2;             // 0..15 within 16-row chunk
    int scol = (lane & 3) * 8;        // 4 lanes cover one 64 B row strip

    f32x4 acc[8][4] = {};

    // stage tile t: A = 16 chunks of 16 rows (wave w: chunks w,w+4,w+8,w+12),
    // B = 8 chunks (wave w: chunks w, w+4). 6 gloads/lane/tile.
    auto STAGE = [&](int t, int slot) {
#pragma unroll
        for (int i = 0; i < 4; i++) {
            int s = wid + i * 4;
            gload_lds16(A + (size_t)(row0 + s * 16 + srow) * K + t * BK + scol, &As[slot][s * 512]);
        }
#pragma unroll
        for (int i = 0; i < 2; i++) {
            int s = wid + i * 4;
            gload_lds16(Bt + (size_t)(col0 + s * 16 + srow) * K + t * BK + scol, &Bs[slot][s * 512]);
        }
    };

    STAGE(0, 0);
    STAGE(1, 1);

    for (int t = 0; t < KT; ++t) {
        int slot = t % 3;
        // Own-wave bound on tile t's 6 loads; barrier join makes all waves'
        // tile-t data visible after the barrier. Slot t+2 (== t-1 mod 3) is
        // safe to overwrite: every wave's iter t-1 ds_reads completed before
        // it entered barrier t.
        if (t == KT - 1) asm volatile("s_waitcnt vmcnt(0)" ::: "memory");
        else             asm volatile("s_waitcnt vmcnt(6)" ::: "memory");
        __builtin_amdgcn_s_barrier();
        __builtin_amdgcn_sched_barrier(0);
        // ds_reads first: lgkm latency hides under the STAGE VMEM issues.
        bf16x8 fa[8], fb[4];
#pragma unroll
        for (int m = 0; m < 8; m++)
            fa[m] = *(const bf16x8*)&As[slot][(wr * 128 + m * 16 + l15) * BK + lg * 8];
#pragma unroll
        for (int n = 0; n < 4; n++)
            fb[n] = *(const bf16x8*)&Bs[slot][(wc * 64 + n * 16 + l15) * BK + lg * 8];
        if (t + 2 < KT) STAGE(t + 2, (t + 2) % 3);
        __builtin_amdgcn_s_setprio(1);
#pragma unroll
        for (int m = 0; m < 8; m++)
#pragma unroll
            for (int n = 0; n < 4; n++)
                acc[m][n] = __builtin_amdgcn_mfma_f32_16x16x32_bf16(fa[m], fb[n], acc[m][n], 0, 0, 0);
        __builtin_amdgcn_s_setprio(0);
    }

    if (MODE == 0) {
        // Coalesced epilogue: per wave, 2 KB LDS strip in As[0] (all waves'
        // last reads of As[0] were iter 30; drained by barrier 31).
        __bf16* stg = &As[0][wid * 1024];   // [16 rows][64 cols] bf16
        int rsub = lane >> 3;               // 0..7
        int csub = lane & 7;                // 0..7 (16-B chunk)
#pragma unroll
        for (int m = 0; m < 8; m++) {
#pragma unroll
            for (int n = 0; n < 4; n++) {
                int col = col0 + wc * 64 + n * 16 + l15;
#pragma unroll
                for (int r = 0; r < 4; r++) {
                    int row = row0 + wr * 128 + m * 16 + lg * 4 + r;
                    float v = acc[m][n][r] + pos[((row & 1023) << 10) + (col & 1023)];
                    stg[(lg * 4 + r) * 64 + n * 16 + l15] = (__bf16)v;
                }
            }
#pragma unroll
            for (int h = 0; h < 2; h++) {
                int lrow = h * 8 + rsub;
                bf16x8 vv = *(const bf16x8*)&stg[lrow * 64 + csub * 8];
                int grow = row0 + wr * 128 + m * 16 + lrow;
                *(bf16x8*)&Cbf[(size_t)grow * Ncols + col0 + wc * 64 + csub * 8] = vv;
            }
        }
    } else {
#pragma unroll
        for (int m = 0; m < 8; m++) {
#pragma unroll
            for (int n = 0; n < 4; n++) {
                int col = col0 + wc * 64 + n * 16 + l15;
#pragma unroll
                for (int r = 0; r < 4; r++) {
                    int row = row0 + wr * 128 + m * 16 + lg * 4 + r;
                    corr[(size_t)row * 1024 + col] = acc[m][n][r];
                }
            }
        }
    }
}

// ---------------------------------------------------------------------------
// Kernel 4: windowed attention. One wave per (b, n). QKV row = Q|K|V bf16.
// scores over 9 clipped neighbors, softmax in-register, ctx written bf16.
// ---------------------------------------------------------------------------
__global__ __launch_bounds__(256) void attn_kernel(const __bf16* __restrict__ QKV,
                                                   __bf16* __restrict__ ctx) {
    int wg   = blockIdx.x * 4 + (threadIdx.x >> 6);  // = b*1024 + n
    int lane = threadIdx.x & 63;
    int n = wg & 1023;
    int browbase = wg - n;  // b*1024

    const __bf16* qrow = QKV + (size_t)wg * N3_;
    bf16x8 q0 = *(const bf16x8*)(qrow + lane * 8);
    bf16x8 q1 = *(const bf16x8*)(qrow + 512 + lane * 8);
    float qf[16];
#pragma unroll
    for (int i = 0; i < 8; i++) { qf[i] = (float)q0[i]; qf[8 + i] = (float)q1[i]; }

    float sc[WIN_];
#pragma unroll
    for (int w = 0; w < WIN_; w++) {
        int nn = n - HALF_ + w;
        nn = (nn < 0) ? 0 : (nn > 1023 ? 1023 : nn);
        const __bf16* krow = QKV + (size_t)(browbase + nn) * N3_ + D_;
        bf16x8 k0 = *(const bf16x8*)(krow + lane * 8);
        bf16x8 k1 = *(const bf16x8*)(krow + 512 + lane * 8);
        float s = 0.f;
#pragma unroll
        for (int i = 0; i < 8; i++)
            s += qf[i] * (float)k0[i] + qf[8 + i] * (float)k1[i];
        s += __shfl_xor(s, 32); s += __shfl_xor(s, 16); s += __shfl_xor(s, 8);
        s += __shfl_xor(s, 4);  s += __shfl_xor(s, 2);  s += __shfl_xor(s, 1);
        sc[w] = s * 0.03125f;  // 1/sqrt(1024)
    }

    float mx = sc[0];
#pragma unroll
    for (int w = 1; w < WIN_; w++) mx = fmaxf(mx, sc[w]);
    float e[WIN_], sum = 0.f;
#pragma unroll
    for (int w = 0; w < WIN_; w++) { e[w] = __expf(sc[w] - mx); sum += e[w]; }
    float inv = 1.0f / sum;

    float accv[16];
#pragma unroll
    for (int i = 0; i < 16; i++) accv[i] = 0.f;
#pragma unroll
    for (int w = 0; w < WIN_; w++) {
        int nn = n - HALF_ + w;
        nn = (nn < 0) ? 0 : (nn > 1023 ? 1023 : nn);
        const __bf16* vrow = QKV + (size_t)(browbase + nn) * N3_ + 2 * D_;
        bf16x8 v0 = *(const bf16x8*)(vrow + lane * 8);
        bf16x8 v1 = *(const bf16x8*)(vrow + 512 + lane * 8);
        float aw = e[w] * inv;
#pragma unroll
        for (int i = 0; i < 8; i++) {
            accv[i]     += aw * (float)v0[i];
            accv[8 + i] += aw * (float)v1[i];
        }
    }

    bf16x8 o0, o1;
#pragma unroll
    for (int i = 0; i < 8; i++) { o0[i] = (__bf16)accv[i]; o1[i] = (__bf16)accv[8 + i]; }
    __bf16* crow = ctx + (size_t)wg * D_;
    *(bf16x8*)(crow + lane * 8) = o0;
    *(bf16x8*)(crow + 512 + lane * 8) = o1;
}

// ---------------------------------------------------------------------------
// Kernel 6: out[rc, t] = xb[rc, t] + corr[rc], flat float4 grid-stride.
// Nontemporal on the pure streams (xb, out); corr stays cached.
// ---------------------------------------------------------------------------
__global__ __launch_bounds__(256) void add_kernel(const float* __restrict__ xb,
                                                  const float* __restrict__ corr,
                                                  float* __restrict__ outp) {
    const long long total4 = (long long)M_ * C_ * T_ / 4;   // 67,108,864
    long long stride = (long long)gridDim.x * 256;
#pragma unroll 4
    for (long long i = (long long)blockIdx.x * 256 + threadIdx.x; i < total4; i += stride) {
        float c = corr[i >> 3];                 // 8 lanes share one corr value
        f32x4 x = __builtin_nontemporal_load((const f32x4*)xb + i);
        x.x += c; x.y += c; x.z += c; x.w += c;
        __builtin_nontemporal_store(x, (f32x4*)outp + i);
    }
}

// ---------------------------------------------------------------------------
extern "C" void kernel_launch(void* const* d_in, const int* in_sizes, int n_in,
                              void* d_out, int out_size, void* d_ws, size_t ws_size,
                              hipStream_t stream) {
    const float* xb  = (const float*)d_in[0];
    const float* Wq  = (const float*)d_in[1];
    const float* Wk  = (const float*)d_in[2];
    const float* Wv  = (const float*)d_in[3];
    const float* Wo  = (const float*)d_in[4];
    const float* pos = (const float*)d_in[5];
    float* out = (float*)d_out;

    char* ws = (char*)d_ws;
    // workspace layout (bytes)
    __bf16* tokens = (__bf16*)(ws);                       // M*1024*2      = 16 MB
    __bf16* wqkvt  = (__bf16*)(ws + 16777216);            // 3072*1024*2   = 6 MB
    __bf16* wot    = (__bf16*)(ws + 23068672);            // 1024*1024*2   = 2 MB
    __bf16* qkv    = (__bf16*)(ws + 25165824);            // M*3072*2      = 48 MB
    __bf16* ctx    = (__bf16*)(ws + 75497472);            // M*1024*2      = 16 MB
    float*  corr   = (float*)(ws + 25165824);             // reuse qkv: M*1024*4 = 32 MB
    // total 88 MB

    // 1. tokens = mean(xb, T)   (grid-stride, 2048 blocks)
    mean_kernel<<<dim3(2048), dim3(256), 0, stream>>>(xb, tokens);

    // 2. weight transpose + bf16 cast
    transpose_kernel<<<dim3(32, 32, 4), dim3(32, 8), 0, stream>>>(Wq, Wk, Wv, Wo, wqkvt, wot);

    // 3. QKV = tokens @ [Wq|Wk|Wv] + pos   (32 row-tiles x 24 col-tiles = 768)
    gemm_kernel<0><<<dim3(768), dim3(256), 0, stream>>>(
        tokens, wqkvt, 1024, N3_, pos, qkv, nullptr);

    // 4. windowed attention -> ctx
    attn_kernel<<<dim3(M_ / 4), dim3(256), 0, stream>>>(qkv, ctx);

    // 5. corr = ctx @ Wo  (32 x 8 = 256 blocks)
    gemm_kernel<1><<<dim3(256), dim3(256), 0, stream>>>(
        ctx, wot, 1024, C_, nullptr, nullptr, corr);

    // 6. out = xb + corr (broadcast over T)  (8192 blocks)
    add_kernel<<<dim3(8192), dim3(256), 0, stream>>>(xb, corr, out);
}